// Round 7
// baseline (335.081 us; speedup 1.0000x reference)
//
#include <hip/hip_runtime.h>
#include <stdint.h>

#define T_LEN 512
#define VOCAB 101
#define GSP   140   // bf16 G row pitch in shorts (280 B)
#define XPB   516   // token row pitch bytes (512 + 3 replicated tail + pad)
#define HPW   20    // h row pitch in dwords (16 data + 4 pad; 2-way max alias on b128 = free)

typedef short short8 __attribute__((ext_vector_type(8)));
typedef short s16x4  __attribute__((ext_vector_type(4)));
typedef float f32x4  __attribute__((ext_vector_type(4)));

#define LOG2E 1.442695041f
#define L2E2  2.885390082f   // 2*log2(e)

__device__ __forceinline__ float asF(uint32_t u) {
    union { uint32_t i; float f; } x; x.i = u; return x.f;
}
__device__ __forceinline__ float bf2f(uint16_t u) { return asF(((uint32_t)u) << 16); }
__device__ __forceinline__ float bf_lo(uint32_t u) { return asF(u << 16); }
__device__ __forceinline__ float bf_hi(uint32_t u) { return asF(u & 0xFFFF0000u); }
__device__ __forceinline__ uint16_t f2bf(float f) {
    union { float f; uint32_t i; } x; x.f = f;
    return (uint16_t)((x.i + 0x7FFFu + ((x.i >> 16) & 1u)) >> 16);
}
__device__ __forceinline__ float getw(const void* p, int i, bool isbf) {
    return isbf ? bf2f(((const uint16_t*)p)[i]) : ((const float*)p)[i];
}
__device__ __forceinline__ bool detect_bf16(const void* embp) {
    const uint16_t* u = (const uint16_t*)embp;
    int sane = 0;
    for (int i = 0; i < 64; ++i) {
        uint16_t v = u[i];
        int e = (v >> 7) & 0xFF;
        sane += ((e >= 100 && e <= 140) || ((v & 0x7FFFu) == 0)) ? 1 : 0;
    }
    return sane >= 56;
}

// gates for one unit: S = f32x4 preacts (i,f,g,o; i/f/o log2e-scaled, g 2log2e-scaled),
// CST = cell state (2log2e scale). Emits h (f32). 5 exp2 + 2 rcp. Verified r1-r6.
#define GATES(S, CST, HOUT)                                                     \
  {                                                                             \
    float ai = __builtin_amdgcn_exp2f(-(S)[0]);                                 \
    float af = __builtin_amdgcn_exp2f(-(S)[1]);                                 \
    float ag = __builtin_amdgcn_exp2f(-(S)[2]);                                 \
    float ao = __builtin_amdgcn_exp2f(-(S)[3]);                                 \
    float uu = 1.f + ai, ww = 1.f + ag, zz = 1.f + af;                          \
    float uw = uu * ww;                                                         \
    float num = __builtin_fmaf(__builtin_fmaf(ww, -L2E2, 2.f * L2E2), zz,       \
                               (CST) * uw);                                     \
    float cs = num * __builtin_amdgcn_rcpf(zz * uw);                            \
    (CST) = cs;                                                                 \
    float ac = __builtin_amdgcn_exp2f(-cs);                                     \
    float t1 = 1.f + ac;                                                        \
    (HOUT) = (2.f - t1) * __builtin_amdgcn_rcpf((1.f + ao) * t1);               \
  }

#define BAR()                                                                   \
  { __builtin_amdgcn_s_barrier(); __builtin_amdgcn_sched_barrier(0); }

// READ tick: read own group's h(t-1), unpack G (read last tick, retired) into
// the MFMA C-operand, compute preacts sreg = Wh*h + G. No writes, no barrier.
#define PHASE_R()                                                               \
  {                                                                             \
    short8 bfrag = *(const short8*)&hb[n * HPW + 4 * q];                        \
    __builtin_amdgcn_sched_barrier(0);                                          \
    f32x4 gc;                                                                   \
    { union { s16x4 v; uint32_t d[2]; } ug; ug.v = grawP;                       \
      gc[0] = bf_lo(ug.d[0]); gc[1] = bf_hi(ug.d[0]);                           \
      gc[2] = bf_lo(ug.d[1]); gc[3] = bf_hi(ug.d[1]); }                         \
    __builtin_amdgcn_sched_barrier(0);                                          \
    asm volatile("s_waitcnt lgkmcnt(0)" ::: "memory");                          \
    __builtin_amdgcn_sched_barrier(0);                                          \
    sreg = __builtin_amdgcn_mfma_f32_16x16x32_bf16(afr, bfrag, gc, 0, 0, 0);    \
  }

// GATE tick: gates on sreg, write h(t), then prefetch G(t+1) + token(t+2).
// Issue order write < G < tok; in-order DS retirement makes lgkmcnt(2) retire
// exactly the write -> visible at the following barrier; G/tok stay in flight
// and complete during the next tick, off-chain.
#define PHASE_G(TOFF)                                                           \
  {                                                                             \
    float h0;                                                                   \
    GATES(sreg, c0, h0);                                                        \
    uint32_t hp;                                                                \
    asm("v_cvt_pk_bf16_f32 %0, %1, %2" : "=v"(hp) : "v"(h0), "v"(h0));          \
    ((uint16_t*)hb)[n * (2 * HPW) + u4] = (uint16_t)hp;                         \
    __builtin_amdgcn_sched_barrier(0);                                          \
    grawP = *(const s16x4*)&Gl2[tokA * GSP + (u4 << 2)];                        \
    __builtin_amdgcn_sched_barrier(0);                                          \
    tokA = xr[TOFF];                                                            \
    __builtin_amdgcn_sched_barrier(0);                                          \
    asm volatile("s_waitcnt lgkmcnt(2)" ::: "memory");                          \
    __builtin_amdgcn_sched_barrier(0);                                          \
  }

__global__ __launch_bounds__(1024, 1) void lstm_fused(
    const int* __restrict__ x, const void* __restrict__ emb,
    const void* __restrict__ Wx, const void* __restrict__ Wh,
    const void* __restrict__ bias, const void* __restrict__ Wfc,
    const void* __restrict__ bfc, void* __restrict__ out)
{
    __shared__ __align__(16) uint16_t Gl2[VOCAB * GSP];     // 28,280 B bf16 preact bias
    __shared__ __align__(16) uint8_t  xt8[32 * XPB];        // 16,512 B packed tokens
    __shared__ __align__(16) uint32_t hbuf[2 * 16 * HPW];   //  2,560 B: one h buf/group

    const int tid = threadIdx.x;
    const int wl  = tid & 63;
    const int w   = tid >> 6;       // wave 0..15
    const int grp = w >> 3;         // 0 = group A (rows 0-15), 1 = B (rows 16-31)
    const int wv  = w & 7;          // wave-in-group: owns units 4wv..4wv+3
    const int n   = wl & 15;        // batch row within group
    const int q   = wl >> 4;        // lane owns unit 4wv+q for row n
    const int u4  = 4 * wv + q;
    const int b0  = blockIdx.x * 32;

    const bool isbf = detect_bf16(emb);

    // ---- build G[v][u][g] = bf16( scale(g) * (emb[v]@Wx + b)[32g+u] ) ----
    for (int idx = tid; idx < VOCAB * 128; idx += 1024) {
        int v = idx >> 7, cc = idx & 127;
        int u = cc >> 2, g = cc & 3;
        int col = 32 * g + u;
        float acc = getw(bias, col, isbf);
        #pragma unroll 8
        for (int k = 0; k < 32; ++k)
            acc += getw(emb, v * 32 + k, isbf) * getw(Wx, k * 128 + col, isbf);
        Gl2[v * GSP + cc] = f2bf(acc * ((g == 2) ? L2E2 : LOG2E));
    }
    // ---- pack x tokens to u8 (32 rows); replicate first 3 at [512..514] ----
    for (int i = tid; i < 4096; i += 1024) {
        int row = i >> 7, c4 = i & 127;
        int4 vv = *(const int4*)&x[(b0 + row) * T_LEN + (c4 << 2)];
        uint32_t p = (uint32_t)(vv.x & 255) | ((uint32_t)(vv.y & 255) << 8) |
                     ((uint32_t)(vv.z & 255) << 16) | ((uint32_t)(vv.w & 255) << 24);
        ((uint32_t*)&xt8[row * XPB])[c4] = p;
    }
    for (int i = tid; i < 96; i += 1024) {
        int row = i / 3, j = i % 3;
        xt8[row * XPB + 512 + j] = (uint8_t)x[(b0 + row) * T_LEN + j];
    }
    // ---- zero h buffers ----
    for (int i = tid; i < 2 * 16 * HPW; i += 1024) hbuf[i] = 0;

    // ---- A fragment: D-row m <-> (gate m&3, unit 4wv + (m>>2));
    //      A[m=n][k=8q+jj] = sc(n&3)*Wh[8q+jj][32*(n&3)+4wv+(n>>2)] ----
    short8 afr;
    {
        const int gte = n & 3, ul = n >> 2;
        const float sc = (gte == 2) ? L2E2 : LOG2E;
        const int base = 32 * gte + 4 * wv + ul;
        union { short8 v; uint16_t s[8]; } u0;
        #pragma unroll
        for (int jj = 0; jj < 8; ++jj)
            u0.s[jj] = f2bf(getw(Wh, (8 * q + jj) * 128 + base, isbf) * sc);
        afr = u0.v;
    }
    __syncthreads();

    uint32_t*       hb = &hbuf[grp * (16 * HPW)];
    const uint8_t*  xr = &xt8[(grp * 16 + n) * XPB];

    float c0 = 0.f;
    f32x4 sreg;
    s16x4 grawP;
    int tokA, tno = 2;
    {
        int t0 = xr[0];
        tokA  = xr[1];
        grawP = *(const s16x4*)&Gl2[t0 * GSP + (u4 << 2)];
    }

    if (grp == 0) {
        // Group A: tick0 = read+MFMA(t), tick1 = gates+write(t)
        for (int t = 0; t < T_LEN; ++t) {
            PHASE_R();
            BAR();
            PHASE_G(tno); ++tno;
            BAR();
        }
    } else {
        // Group B: phase-shifted by one tick. Prologue: s(0) = G(0) (h(-1)=0).
        {
            union { s16x4 v; uint32_t d[2]; } ug; ug.v = grawP;
            sreg[0] = bf_lo(ug.d[0]); sreg[1] = bf_hi(ug.d[0]);
            sreg[2] = bf_lo(ug.d[1]); sreg[3] = bf_hi(ug.d[1]);
        }
        for (int t = 0; t < T_LEN; ++t) {
            PHASE_G(tno); ++tno;
            BAR();
            PHASE_R();      // computes s(t+1); final iteration's result unused
            BAR();
        }
    }

    __syncthreads();   // full drain before epilogue reads

    // ---- epilogue: out = h(T-1) @ W_fc + b_fc (32 rows) ----
    if (tid < 64) {
        int r32 = tid >> 1, cc = tid & 1;
        const uint32_t* hrow = &hbuf[(r32 >> 4) * (16 * HPW) + (r32 & 15) * HPW];
        float acc = getw(bfc, cc, isbf);
        #pragma unroll 8
        for (int k = 0; k < 32; ++k) {
            uint32_t d = hrow[k >> 1];
            float hval = (k & 1) ? bf_hi(d) : bf_lo(d);
            acc += hval * getw(Wfc, k * 2 + cc, isbf);
        }
        int oidx = (b0 + r32) * 2 + cc;
        if (isbf) ((uint16_t*)out)[oidx] = f2bf(acc);
        else      ((float*)out)[oidx]    = acc;
    }
}

extern "C" void kernel_launch(void* const* d_in, const int* in_sizes, int n_in,
                              void* d_out, int out_size, void* d_ws, size_t ws_size,
                              hipStream_t stream) {
    (void)in_sizes; (void)n_in; (void)d_ws; (void)ws_size; (void)out_size;
    const int* x = (const int*)d_in[0];
    lstm_fused<<<dim3(128), dim3(1024), 0, stream>>>(
        x, d_in[1], d_in[2], d_in[3], d_in[4], d_in[5], d_in[6], d_out);
}